// Round 1
// baseline (216.005 us; speedup 1.0000x reference)
//
#include <hip/hip_runtime.h>

// Problem: B=8, T=2048, D_MODEL=1024, D_HEAD=64, fp32 in/out.
// Pipeline: pack W -> bf16 Wt[192][1024] | QKV GEMM (bf16 MFMA) -> qkv[16384][192] bf16
//           | causal flash attention (bf16 MFMA, online softmax in log2 domain).
#define TT   2048
#define DM   1024
#define DH   64
#define NB   8
#define NQKV 192
#define LDST 88   // LDS row stride (elements): 16B-aligned rows, 2-way bank aliasing (free)

typedef __attribute__((ext_vector_type(4))) float          f32x4;
typedef __attribute__((ext_vector_type(4))) int            i32x4;
typedef __attribute__((ext_vector_type(4))) unsigned short u16x4;
typedef __attribute__((ext_vector_type(8))) unsigned short u16x8;

__device__ __forceinline__ unsigned short f2bf(float f) {  // RNE fp32->bf16
  unsigned int u = __float_as_uint(f);
  u += 0x7fffu + ((u >> 16) & 1u);
  return (unsigned short)(u >> 16);
}

// Inline-asm MFMA: avoids builtin signature ambiguity; s_nop 1 covers
// VALU-write -> MFMA-read hazards. D==C accumulation chaining is hazard-free.
#define MFMA(acc, a, b) \
  asm volatile("s_nop 1\n\tv_mfma_f32_16x16x32_bf16 %0, %1, %2, %0" \
               : "+v"(acc) : "v"(a), "v"(b))

// MFMA-write -> VALU-read fence (16 wait states), tied to accs so reads can't move above.
#define FENCE4(a,b,c,d) \
  asm volatile("s_nop 7\n\ts_nop 7" : "+v"(a), "+v"(b), "+v"(c), "+v"(d))

// ---------------- pack: W_Q|W_K|W_V (fp32 [1024][64]) -> Wt bf16 [192][1024] ----------
__global__ __launch_bounds__(256) void pack_w_kernel(
    const float* __restrict__ wq, const float* __restrict__ wk,
    const float* __restrict__ wv, unsigned short* __restrict__ wt) {
  int idx = blockIdx.x * 256 + threadIdx.x;
  if (idx >= NQKV * DM) return;
  int n = idx >> 10;          // output col 0..191
  int k = idx & (DM - 1);     // 0..1023
  const float* src = (n < 64) ? wq : ((n < 128) ? wk : wv);
  wt[(size_t)n * DM + k] = f2bf(src[(size_t)k * DH + (n & 63)]);
}

// ---------------- QKV GEMM: x[16384][1024] fp32 @ Wt^T -> qkv[16384][192] bf16 --------
// Grid 256 (64-row m-tiles), 256 thr = 4 waves; wave w: rows w*16..+15, all 192 cols.
__global__ __launch_bounds__(256) void qkv_gemm_kernel(
    const float* __restrict__ x, const unsigned short* __restrict__ wt,
    unsigned short* __restrict__ qkv) {
  __shared__ __align__(16) unsigned short a_lds[64 * LDST];
  __shared__ __align__(16) unsigned short b_lds[NQKV * LDST];

  const int tid  = threadIdx.x;
  const int w    = tid >> 6;
  const int lane = tid & 63;
  const int ln   = lane & 15;
  const int quad = lane >> 4;
  const int m0   = blockIdx.x * 64;

  f32x4 acc[12];
  #pragma unroll
  for (int i = 0; i < 12; ++i) acc[i] = (f32x4){0.f, 0.f, 0.f, 0.f};

  const int str = tid >> 4;        // staging row-in-step 0..15
  const int stc = (tid & 15) * 4;  // staging col

  for (int k0 = 0; k0 < DM; k0 += 64) {
    __syncthreads();  // previous iteration's LDS reads complete
    // stage A: 64x64 fp32 -> bf16 (coalesced float4, 256B/16-lane row segments)
    #pragma unroll
    for (int s = 0; s < 4; ++s) {
      int row = s * 16 + str;
      f32x4 v = *(const f32x4*)(x + (size_t)(m0 + row) * DM + k0 + stc);
      u16x4 h;
      h[0] = f2bf(v[0]); h[1] = f2bf(v[1]); h[2] = f2bf(v[2]); h[3] = f2bf(v[3]);
      *(u16x4*)&a_lds[row * LDST + stc] = h;
    }
    // stage B: Wt rows 0..191, cols k0..k0+63 (16B chunks)
    #pragma unroll
    for (int c = 0; c < 6; ++c) {
      int cid = c * 256 + tid;       // 0..1535
      int n   = cid >> 3;
      int kc  = (cid & 7) * 8;
      i32x4 vv = *(const i32x4*)(wt + (size_t)n * DM + k0 + kc);
      *(i32x4*)&b_lds[n * LDST + kc] = vv;
    }
    __syncthreads();
    #pragma unroll
    for (int ks = 0; ks < 64; ks += 32) {
      i32x4 af = *(const i32x4*)&a_lds[(w * 16 + ln) * LDST + ks + quad * 8];
      #pragma unroll
      for (int nt = 0; nt < 12; ++nt) {
        i32x4 bf = *(const i32x4*)&b_lds[(nt * 16 + ln) * LDST + ks + quad * 8];
        MFMA(acc[nt], af, bf);
      }
    }
  }

  FENCE4(acc[0], acc[1], acc[2],  acc[3]);
  FENCE4(acc[4], acc[5], acc[6],  acc[7]);
  FENCE4(acc[8], acc[9], acc[10], acc[11]);

  // Fold softmax scale 1/sqrt(64) * log2(e) into Q (single bf16 rounding).
  const float QS = 0.18033688011112042f;
  #pragma unroll
  for (int nt = 0; nt < 12; ++nt) {
    const float sc = (nt < 4) ? QS : 1.0f;
    #pragma unroll
    for (int r = 0; r < 4; ++r) {
      int row = m0 + w * 16 + quad * 4 + r;   // C/D layout: row = quad*4+reg
      int col = nt * 16 + ln;                 //             col = lane&15
      qkv[(size_t)row * NQKV + col] = f2bf(acc[nt][r] * sc);
    }
  }
}

// ---------------- causal flash attention ---------------------------------------------
// Grid (32 q-tiles, 8 batches), 256 thr = 4 waves; wave w owns q rows qt*64+w*16..+15.
__global__ __launch_bounds__(256) void attn_kernel(
    const unsigned short* __restrict__ qkv, float* __restrict__ out) {
  __shared__ __align__(16) unsigned short k_lds[64 * LDST];  // K[t][d]
  __shared__ __align__(16) unsigned short v_lds[64 * LDST];  // V^T: [d][t]
  __shared__ __align__(16) unsigned short p_lds[64 * LDST];  // P per-wave 16-row slabs

  const int tid  = threadIdx.x;
  const int w    = tid >> 6;
  const int lane = tid & 63;
  const int ln   = lane & 15;
  const int quad = lane >> 4;
  const int qt   = blockIdx.x;
  const int bb   = blockIdx.y * TT;
  const int q0   = qt * 64;

  // Q fragments (A-layout: m=lane&15, k=quad*8+j), resident all kernel. Already log2-scaled.
  const unsigned short* qrow = qkv + (size_t)(bb + q0 + w * 16 + ln) * NQKV;
  const i32x4 qf0 = *(const i32x4*)(qrow + quad * 8);
  const i32x4 qf1 = *(const i32x4*)(qrow + 32 + quad * 8);

  f32x4 acc_o[4];
  #pragma unroll
  for (int i = 0; i < 4; ++i) acc_o[i] = (f32x4){0.f, 0.f, 0.f, 0.f};
  float m_st[4], l_st[4];
  #pragma unroll
  for (int r = 0; r < 4; ++r) { m_st[r] = -1e30f; l_st[r] = 0.f; }

  const int qg_base = q0 + w * 16 + quad * 4;

  for (int kt = 0; kt <= qt; ++kt) {
    __syncthreads();  // prior PV reads of k/v/p_lds done
    // stage K tile as-is and V tile transposed
    #pragma unroll
    for (int c = 0; c < 2; ++c) {
      int cid = c * 256 + tid;     // 0..511
      int row = cid >> 3;          // t-local 0..63
      int dc  = (cid & 7) * 8;     // d chunk
      const unsigned short* src = qkv + (size_t)(bb + kt * 64 + row) * NQKV;
      i32x4 kv = *(const i32x4*)(src + 64 + dc);
      *(i32x4*)&k_lds[row * LDST + dc] = kv;
      u16x8 vv = *(const u16x8*)(src + 128 + dc);
      #pragma unroll
      for (int j = 0; j < 8; ++j) v_lds[(dc + j) * LDST + row] = vv[j];
    }
    __syncthreads();

    // S = Q K^T  (log2 domain; B-operand: K[t][d] rows contiguous)
    f32x4 acc_s[4];
    #pragma unroll
    for (int i = 0; i < 4; ++i) acc_s[i] = (f32x4){0.f, 0.f, 0.f, 0.f};
    #pragma unroll
    for (int ns = 0; ns < 4; ++ns) {
      i32x4 kf0 = *(const i32x4*)&k_lds[(ns * 16 + ln) * LDST + quad * 8];
      i32x4 kf1 = *(const i32x4*)&k_lds[(ns * 16 + ln) * LDST + 32 + quad * 8];
      MFMA(acc_s[ns], qf0, kf0);
      MFMA(acc_s[ns], qf1, kf1);
    }
    FENCE4(acc_s[0], acc_s[1], acc_s[2], acc_s[3]);

    const bool diag = (kt == qt);
    #pragma unroll
    for (int r = 0; r < 4; ++r) {
      const int qg = qg_base + r;
      float mx = -1e30f;
      #pragma unroll
      for (int ns = 0; ns < 4; ++ns) {
        float s = acc_s[ns][r];
        if (diag) {
          int kg = kt * 64 + ns * 16 + ln;
          s = (kg <= qg) ? s : -1e30f;
          acc_s[ns][r] = s;
        }
        mx = fmaxf(mx, s);
      }
      mx = fmaxf(mx, __shfl_xor(mx, 1));
      mx = fmaxf(mx, __shfl_xor(mx, 2));
      mx = fmaxf(mx, __shfl_xor(mx, 4));
      mx = fmaxf(mx, __shfl_xor(mx, 8));
      float mnew  = fmaxf(m_st[r], mx);
      float alpha = exp2f(m_st[r] - mnew);
      m_st[r] = mnew;
      float ps = 0.f;
      #pragma unroll
      for (int ns = 0; ns < 4; ++ns) {
        float p = exp2f(acc_s[ns][r] - mnew);
        ps += p;
        // C-layout -> A-layout transform via LDS round trip
        p_lds[(w * 16 + quad * 4 + r) * LDST + ns * 16 + ln] = f2bf(p);
      }
      ps += __shfl_xor(ps, 1);
      ps += __shfl_xor(ps, 2);
      ps += __shfl_xor(ps, 4);
      ps += __shfl_xor(ps, 8);
      l_st[r] = l_st[r] * alpha + ps;
      #pragma unroll
      for (int nt = 0; nt < 4; ++nt) acc_o[nt][r] *= alpha;
    }
    __syncthreads();  // P visible to all lanes of the wave (uniform barrier)

    // O += P V   (A from p_lds, B from transposed v_lds)
    #pragma unroll
    for (int kk = 0; kk < 64; kk += 32) {
      i32x4 pf = *(const i32x4*)&p_lds[(w * 16 + ln) * LDST + kk + quad * 8];
      #pragma unroll
      for (int nt = 0; nt < 4; ++nt) {
        i32x4 vf = *(const i32x4*)&v_lds[(nt * 16 + ln) * LDST + kk + quad * 8];
        MFMA(acc_o[nt], pf, vf);
      }
    }
  }

  FENCE4(acc_o[0], acc_o[1], acc_o[2], acc_o[3]);
  #pragma unroll
  for (int r = 0; r < 4; ++r) {
    float inv = 1.0f / l_st[r];
    size_t base = (size_t)(bb + qg_base + r) * DH;
    #pragma unroll
    for (int nt = 0; nt < 4; ++nt)
      out[base + nt * 16 + ln] = acc_o[nt][r] * inv;
  }
}

extern "C" void kernel_launch(void* const* d_in, const int* in_sizes, int n_in,
                              void* d_out, int out_size, void* d_ws, size_t ws_size,
                              hipStream_t stream) {
  const float* x  = (const float*)d_in[0];
  const float* wq = (const float*)d_in[1];
  const float* wk = (const float*)d_in[2];
  const float* wv = (const float*)d_in[3];
  float* out = (float*)d_out;

  unsigned short* wt  = (unsigned short*)d_ws;                               // 384 KB
  unsigned short* qkv = (unsigned short*)((char*)d_ws + (size_t)NQKV * DM * 2); // 6 MB

  pack_w_kernel<<<(NQKV * DM + 255) / 256, 256, 0, stream>>>(wq, wk, wv, wt);
  qkv_gemm_kernel<<<NB * TT / 64, 256, 0, stream>>>(x, wt, qkv);
  attn_kernel<<<dim3(TT / 64, NB), 256, 0, stream>>>(qkv, out);
}

// Round 3
// 191.461 us; speedup vs baseline: 1.1282x; 1.1282x over previous
//
#include <hip/hip_runtime.h>

// B=8, T=2048, D_MODEL=1024, D_HEAD=64, fp32 in/out.
// pack W -> Wt bf16[192][1024]
// gemm  -> qkvqk bf16[16384][128] (Q log2-scaled | K), vT bf16[8][64][2048]
// attn_part: split-K flash, chunks of 256 keys -> bf16 partial O + f32 (m,l)
// attn_combine: merge <=8 chunks per (b, 64-row q-tile)
#define TT   2048
#define DM   1024
#define DH   64
#define NB   8
#define KST  72    // k_lds / p_lds row stride (elems): 36 dwords = 4 mod 32 banks
#define VST  264   // v_lds row stride: 132 dwords = 4 mod 32 banks

typedef __attribute__((ext_vector_type(4))) float          f32x4;
typedef __attribute__((ext_vector_type(4))) int            i32x4;
typedef __attribute__((ext_vector_type(4))) unsigned short u16x4;
typedef __attribute__((ext_vector_type(8))) unsigned short u16x8;

__device__ __forceinline__ unsigned short f2bf(float f) {  // RNE fp32->bf16
  unsigned int u = __float_as_uint(f);
  u += 0x7fffu + ((u >> 16) & 1u);
  return (unsigned short)(u >> 16);
}

// s_nop 1 covers VALU-write -> MFMA-read SrcA/B hazard (A is VALU-packed in gemm).
#define MFMA(acc, a, b) \
  asm volatile("s_nop 1\n\tv_mfma_f32_16x16x32_bf16 %0, %1, %2, %0" \
               : "+v"(acc) : "v"(a), "v"(b))
// MFMA-write -> VALU-read fence (16 wait states) tied to the accumulators.
#define FENCE4(a,b,c,d) \
  asm volatile("s_nop 7\n\ts_nop 7" : "+v"(a), "+v"(b), "+v"(c), "+v"(d))

// ws layout (bytes)
#define WS_WT    0u
#define WS_QK    393216u     // 16384*128*2 = 4,194,304
#define WS_VT    4587520u    // 8*64*2048*2 = 2,097,152
#define WS_OP    6684672u    // 8*144*4096*2 = 9,437,184 (bf16 partial O)
#define WS_ML    16121856u   // 8*144*128*4 = 589,824   (f32 m,l per row)

// ---------------- pack: W_Q|W_K|W_V fp32[1024][64] -> Wt bf16[192][1024] -------------
__global__ __launch_bounds__(256) void pack_w_kernel(
    const float* __restrict__ wq, const float* __restrict__ wk,
    const float* __restrict__ wv, unsigned short* __restrict__ wt) {
  int idx = blockIdx.x * 256 + threadIdx.x;
  if (idx >= 192 * DM) return;
  int n = idx >> 10;
  int k = idx & (DM - 1);
  const float* src = (n < 64) ? wq : ((n < 128) ? wk : wv);
  wt[(size_t)n * DM + k] = f2bf(src[(size_t)k * DH + (n & 63)]);
}

// ---------------- QKV GEMM: 1024 single-wave blocks, 16 rows x 192 cols each ---------
// No LDS, no barriers: A (fp32->bf16) and B fragments straight from global with
// prefetch-1 full unroll -> ~14 KB in flight per wave (HBM-BW-bound at 4 waves/CU).
__global__ __launch_bounds__(64, 1) void qkv_gemm_kernel(
    const float* __restrict__ x, const unsigned short* __restrict__ wt,
    unsigned short* __restrict__ qkvqk, unsigned short* __restrict__ vt) {
  const int tid  = threadIdx.x;
  const int ln   = tid & 15;
  const int quad = tid >> 4;
  const int m0   = blockIdx.x * 16;

  const float*          ax = x  + (size_t)(m0 + ln) * DM + quad * 8;
  const unsigned short* bw = wt + (size_t)ln * DM + quad * 8;

  f32x4 acc[12];
  #pragma unroll
  for (int i = 0; i < 12; ++i) acc[i] = (f32x4){0.f, 0.f, 0.f, 0.f};

  union { u16x8 h; i32x4 i; } ap;

  f32x4 a0 = *(const f32x4*)(ax);
  f32x4 a1 = *(const f32x4*)(ax + 4);
  i32x4 bc[12];
  #pragma unroll
  for (int nt = 0; nt < 12; ++nt)
    bc[nt] = *(const i32x4*)(bw + nt * 16 * DM);

  #pragma unroll
  for (int kb = 32; kb < DM; kb += 32) {
    // prefetch next K-step while current MFMAs issue
    f32x4 an0 = *(const f32x4*)(ax + kb);
    f32x4 an1 = *(const f32x4*)(ax + kb + 4);
    i32x4 bn[12];
    #pragma unroll
    for (int nt = 0; nt < 12; ++nt)
      bn[nt] = *(const i32x4*)(bw + nt * 16 * DM + kb);
    #pragma unroll
    for (int j = 0; j < 4; ++j) { ap.h[j] = f2bf(a0[j]); ap.h[4 + j] = f2bf(a1[j]); }
    i32x4 af = ap.i;
    #pragma unroll
    for (int nt = 0; nt < 12; ++nt) MFMA(acc[nt], af, bc[nt]);
    a0 = an0; a1 = an1;
    #pragma unroll
    for (int nt = 0; nt < 12; ++nt) bc[nt] = bn[nt];
  }
  {
    #pragma unroll
    for (int j = 0; j < 4; ++j) { ap.h[j] = f2bf(a0[j]); ap.h[4 + j] = f2bf(a1[j]); }
    i32x4 af = ap.i;
    #pragma unroll
    for (int nt = 0; nt < 12; ++nt) MFMA(acc[nt], af, bc[nt]);
  }

  FENCE4(acc[0], acc[1], acc[2],  acc[3]);
  FENCE4(acc[4], acc[5], acc[6],  acc[7]);
  FENCE4(acc[8], acc[9], acc[10], acc[11]);

  const float QS = 0.18033688011112042f;  // (1/8) * log2(e)
  const int bz = m0 >> 11;                // batch
  const int tb = (m0 & 2047) + quad * 4;  // token base within batch
  #pragma unroll
  for (int nt = 0; nt < 8; ++nt) {        // Q (scaled) | K
    const float sc = (nt < 4) ? QS : 1.0f;
    #pragma unroll
    for (int r = 0; r < 4; ++r) {
      int row = m0 + quad * 4 + r;        // C/D layout: row = quad*4+reg, col = lane&15
      qkvqk[(size_t)row * 128 + nt * 16 + ln] = f2bf(acc[nt][r] * sc);
    }
  }
  #pragma unroll
  for (int nt = 8; nt < 12; ++nt) {       // V -> vT[b][d][t], 8B stores
    int d = (nt - 8) * 16 + ln;
    u16x4 h;
    #pragma unroll
    for (int r = 0; r < 4; ++r) h[r] = f2bf(acc[nt][r]);
    *(u16x4*)(vt + ((size_t)bz * 64 + d) * TT + tb) = h;
  }
}

// ---------------- attn partial: one block = (chunk of 4 k-tiles) x (64-row q-tile) ----
__global__ __launch_bounds__(256) void attn_part_kernel(
    const unsigned short* __restrict__ qkvqk, const unsigned short* __restrict__ vt,
    unsigned short* __restrict__ opart, float* __restrict__ ml) {
  const int c  = blockIdx.x;       // chunk 0..7
  const int qt = blockIdx.y;       // q-tile 0..31
  const int bz = blockIdx.z;
  const int aq = qt >> 2, rq = qt & 3;
  if (c > aq) return;
  const int ntiles = (c == aq) ? (rq + 1) : 4;

  __shared__ __align__(16) unsigned short k_lds[256 * KST];
  __shared__ __align__(16) unsigned short v_lds[64 * VST];
  __shared__ __align__(16) unsigned short p_lds[64 * KST];

  const int tid  = threadIdx.x;
  const int w    = tid >> 6;
  const int lane = tid & 63;
  const int ln   = lane & 15;
  const int quad = lane >> 4;
  const int bb   = bz * TT;
  const int kbase = c * 256;

  // stage K (full 256 keys; kbase+255 <= 2047) and V^T
  #pragma unroll
  for (int i = 0; i < 8; ++i) {
    int cid = i * 256 + tid;
    int row = cid >> 3, dc = (cid & 7) * 8;
    *(i32x4*)&k_lds[row * KST + dc] =
        *(const i32x4*)(qkvqk + (size_t)(bb + kbase + row) * 128 + 64 + dc);
  }
  #pragma unroll
  for (int i = 0; i < 8; ++i) {
    int cid = i * 256 + tid;
    int d = cid >> 5, tc = (cid & 31) * 8;
    *(i32x4*)&v_lds[d * VST + tc] =
        *(const i32x4*)(vt + ((size_t)bz * 64 + d) * TT + kbase + tc);
  }

  // Q fragments (log2-scaled already); A-layout: m=lane&15, k=quad*8+j
  const unsigned short* qrow = qkvqk + (size_t)(bb + qt * 64 + w * 16 + ln) * 128;
  const i32x4 qf0 = *(const i32x4*)(qrow + quad * 8);
  const i32x4 qf1 = *(const i32x4*)(qrow + 32 + quad * 8);

  f32x4 acc_o[4];
  #pragma unroll
  for (int i = 0; i < 4; ++i) acc_o[i] = (f32x4){0.f, 0.f, 0.f, 0.f};
  float m_st[4], l_st[4];
  #pragma unroll
  for (int r = 0; r < 4; ++r) { m_st[r] = -1e30f; l_st[r] = 0.f; }

  const int qg_base = qt * 64 + w * 16 + quad * 4;
  __syncthreads();  // staging complete (single barrier in the kernel)

  for (int ct = 0; ct < ntiles; ++ct) {
    const int ktg = c * 4 + ct;
    const bool diag = (ktg == qt);

    f32x4 acc_s[4];
    #pragma unroll
    for (int i = 0; i < 4; ++i) acc_s[i] = (f32x4){0.f, 0.f, 0.f, 0.f};
    #pragma unroll
    for (int ns = 0; ns < 4; ++ns) {
      i32x4 kf0 = *(const i32x4*)&k_lds[(ct * 64 + ns * 16 + ln) * KST + quad * 8];
      i32x4 kf1 = *(const i32x4*)&k_lds[(ct * 64 + ns * 16 + ln) * KST + 32 + quad * 8];
      MFMA(acc_s[ns], qf0, kf0);
      MFMA(acc_s[ns], qf1, kf1);
    }
    FENCE4(acc_s[0], acc_s[1], acc_s[2], acc_s[3]);

    #pragma unroll
    for (int r = 0; r < 4; ++r) {
      const int qg = qg_base + r;
      float mx = -1e30f;
      #pragma unroll
      for (int ns = 0; ns < 4; ++ns) {
        float s = acc_s[ns][r];
        if (diag) {
          int kg = ktg * 64 + ns * 16 + ln;
          s = (kg <= qg) ? s : -1e30f;
          acc_s[ns][r] = s;
        }
        mx = fmaxf(mx, s);
      }
      mx = fmaxf(mx, __shfl_xor(mx, 1));
      mx = fmaxf(mx, __shfl_xor(mx, 2));
      mx = fmaxf(mx, __shfl_xor(mx, 4));
      mx = fmaxf(mx, __shfl_xor(mx, 8));
      float mnew  = fmaxf(m_st[r], mx);
      float alpha = exp2f(m_st[r] - mnew);
      m_st[r] = mnew;
      float ps = 0.f;
      #pragma unroll
      for (int ns = 0; ns < 4; ++ns) {
        float p = exp2f(acc_s[ns][r] - mnew);
        ps += p;
        // C-layout -> A-layout transform via wave-private LDS slab
        p_lds[(w * 16 + quad * 4 + r) * KST + ns * 16 + ln] = f2bf(p);
      }
      ps += __shfl_xor(ps, 1);
      ps += __shfl_xor(ps, 2);
      ps += __shfl_xor(ps, 4);
      ps += __shfl_xor(ps, 8);
      l_st[r] = l_st[r] * alpha + ps;
      #pragma unroll
      for (int nt = 0; nt < 4; ++nt) acc_o[nt][r] *= alpha;
    }
    // P is wave-private LDS; per-wave LDS ops are in-order (lgkmcnt handles deps).
    #pragma unroll
    for (int kk = 0; kk < 64; kk += 32) {
      i32x4 pf = *(const i32x4*)&p_lds[(w * 16 + ln) * KST + kk + quad * 8];
      #pragma unroll
      for (int nt = 0; nt < 4; ++nt) {
        i32x4 vf = *(const i32x4*)&v_lds[(nt * 16 + ln) * VST + ct * 64 + kk + quad * 8];
        MFMA(acc_o[nt], pf, vf);
      }
    }
    asm volatile("" ::: "memory");  // keep next iter's P writes after this PV's reads
  }

  FENCE4(acc_o[0], acc_o[1], acc_o[2], acc_o[3]);
  const int base = qt + 2 * aq * (aq - 1) + rq * aq;   // packed chunk-slab index
  const size_t slab = (size_t)bz * 144 + base + c;
  unsigned short* op = opart + slab * 4096;
  #pragma unroll
  for (int nt = 0; nt < 4; ++nt)
    #pragma unroll
    for (int r = 0; r < 4; ++r)
      op[(w * 16 + quad * 4 + r) * 64 + nt * 16 + ln] = f2bf(acc_o[nt][r]);
  if (ln == 0) {
    float* mlp = ml + slab * 128;
    #pragma unroll
    for (int r = 0; r < 4; ++r) {
      int row = w * 16 + quad * 4 + r;
      mlp[row * 2]     = m_st[r];
      mlp[row * 2 + 1] = l_st[r];
    }
  }
}

// ---------------- combine: merge <=8 chunks per (b, q-tile) --------------------------
__global__ __launch_bounds__(256) void attn_combine_kernel(
    const unsigned short* __restrict__ opart, const float* __restrict__ ml,
    float* __restrict__ out) {
  const int qt = blockIdx.x;
  const int bz = blockIdx.y;
  const int aq = qt >> 2, rq = qt & 3;
  const int nch = aq + 1;
  const int base = qt + 2 * aq * (aq - 1) + rq * aq;
  const size_t slab0 = (size_t)bz * 144 + base;

  const int tid = threadIdx.x;
  const int row = tid >> 2;
  const int ds  = (tid & 3) * 16;

  float mc[8], lc[8];
  float M = -1e30f;
  #pragma unroll 8
  for (int ch = 0; ch < nch; ++ch) {
    const float* mlp = ml + (slab0 + ch) * 128 + row * 2;
    mc[ch] = mlp[0];
    lc[ch] = mlp[1];
    M = fmaxf(M, mc[ch]);
  }
  float L = 0.f;
  float acc[16];
  #pragma unroll
  for (int j = 0; j < 16; ++j) acc[j] = 0.f;
  #pragma unroll 8
  for (int ch = 0; ch < nch; ++ch) {
    float wgt = exp2f(mc[ch] - M);
    L += wgt * lc[ch];
    const unsigned short* op = opart + (slab0 + ch) * 4096 + row * 64 + ds;
    i32x4 v0 = *(const i32x4*)(op);
    i32x4 v1 = *(const i32x4*)(op + 8);
    #pragma unroll
    for (int j = 0; j < 4; ++j) {
      unsigned int u0 = (unsigned int)v0[j], u1 = (unsigned int)v1[j];
      acc[j * 2]     += wgt * __uint_as_float(u0 << 16);
      acc[j * 2 + 1] += wgt * __uint_as_float(u0 & 0xffff0000u);
      acc[8 + j * 2]     += wgt * __uint_as_float(u1 << 16);
      acc[8 + j * 2 + 1] += wgt * __uint_as_float(u1 & 0xffff0000u);
    }
  }
  float inv = 1.0f / L;
  float* o = out + ((size_t)bz * TT + qt * 64 + row) * 64 + ds;
  #pragma unroll
  for (int j = 0; j < 16; ++j) o[j] = acc[j] * inv;
}

extern "C" void kernel_launch(void* const* d_in, const int* in_sizes, int n_in,
                              void* d_out, int out_size, void* d_ws, size_t ws_size,
                              hipStream_t stream) {
  const float* x  = (const float*)d_in[0];
  const float* wq = (const float*)d_in[1];
  const float* wk = (const float*)d_in[2];
  const float* wv = (const float*)d_in[3];
  float* out = (float*)d_out;

  char* ws = (char*)d_ws;
  unsigned short* wt    = (unsigned short*)(ws + WS_WT);
  unsigned short* qkvqk = (unsigned short*)(ws + WS_QK);
  unsigned short* vt    = (unsigned short*)(ws + WS_VT);
  unsigned short* opart = (unsigned short*)(ws + WS_OP);
  float*          ml    = (float*)(ws + WS_ML);

  pack_w_kernel<<<(192 * DM + 255) / 256, 256, 0, stream>>>(wq, wk, wv, wt);
  qkv_gemm_kernel<<<NB * TT / 16, 64, 0, stream>>>(x, wt, qkvqk, vt);
  attn_part_kernel<<<dim3(8, 32, NB), 256, 0, stream>>>(qkvqk, vt, opart, ml);
  attn_combine_kernel<<<dim3(32, NB), 256, 0, stream>>>(opart, ml, out);
}